// Round 4
// baseline (2403.184 us; speedup 1.0000x reference)
//
#include <hip/hip_runtime.h>

#define KT 8
#define NN 255
#define LL 16
#define DD 512
#define BB 32
#define TT 2048
#define MM (BB*TT)              // 65536
#define TPS_STRIDE (2056*128)   // per-b stride in floats (8-step padding)

typedef short short8 __attribute__((ext_vector_type(8)));
typedef float floatx4 __attribute__((ext_vector_type(4)));

__device__ __forceinline__ unsigned bf16_rne(float v) {
    unsigned u = __float_as_uint(v);
    return (u + 0x7FFFu + ((u >> 16) & 1u)) >> 16;
}

__device__ __forceinline__ void gll16(const char* g, char* l) {
    __builtin_amdgcn_global_load_lds(
        (const __attribute__((address_space(1))) unsigned int*)g,
        (__attribute__((address_space(3))) unsigned int*)l, 16, 0, 0);
}

// ---------------- prep: split x into bf16 hi/lo planes ----------------
__global__ void k_prep_x(const float* __restrict__ x, short* __restrict__ xh,
                         short* __restrict__ xl) {
    size_t g = (size_t)blockIdx.x * 256 + threadIdx.x;   // 4,194,304 threads
    const float4* xv = (const float4*)x;
    float4 a = xv[g * 2], b = xv[g * 2 + 1];
    float v[8] = {a.x, a.y, a.z, a.w, b.x, b.y, b.z, b.w};
    short8 hh, ll;
    #pragma unroll
    for (int j = 0; j < 8; ++j) {
        unsigned h = bf16_rne(v[j]);
        hh[j] = (short)h;
        ll[j] = (short)bf16_rne(v[j] - __uint_as_float(h << 16));
    }
    ((short8*)xh)[g] = hh;
    ((short8*)xl)[g] = ll;
}

// ---------------- prep: softmax(pi) + pack to MFMA B-frag order (fused) ----
// spf layout: [kt][ks8][hl2][lane64][8 bf16]
__global__ void k_prep_sp(const float* __restrict__ pi, short* __restrict__ spf) {
    __shared__ float sm[256 * 16];
    const int kt = blockIdx.x;
    const int tid = threadIdx.x;     // 256
    const float* p = pi + ((size_t)kt * 256 + tid) * LL;
    float v[LL];
    float mx = -1e30f;
    #pragma unroll
    for (int l = 0; l < LL; ++l) { v[l] = p[l]; mx = fmaxf(mx, v[l]); }
    float s = 0.f;
    #pragma unroll
    for (int l = 0; l < LL; ++l) { v[l] = __expf(v[l] - mx); s += v[l]; }
    const float inv = 1.0f / s;
    #pragma unroll
    for (int l = 0; l < LL; ++l) sm[tid * 16 + l] = v[l] * inv;
    __syncthreads();
    #pragma unroll
    for (int it = 0; it < 2; ++it) {
        int item = it * 256 + tid;           // 512 items
        int ks = item >> 6, lane = item & 63;
        int n = lane & 15, oct = lane >> 4;
        short8 hh, ll;
        #pragma unroll
        for (int j = 0; j < 8; ++j) {
            int leaf = ks * 32 + oct * 8 + j;
            float val = sm[leaf * 16 + n];
            unsigned h = bf16_rne(val);
            hh[j] = (short)h;
            ll[j] = (short)bf16_rne(val - __uint_as_float(h << 16));
        }
        size_t base = ((size_t)(kt * 8 + ks) * 2) * 64;
        ((short8*)spf)[base + lane] = hh;
        ((short8*)spf)[base + 64 + lane] = ll;
    }
}

// ---------------- prep: W -> MFMA B-frag order, split bf16 hi/lo ----------------
// Bp layout: [kt][kb16][nt16][hl2][lane64][8 bf16]
__global__ void k_prep_b(const float* __restrict__ W, short* __restrict__ Bp) {
    int g = blockIdx.x * 256 + threadIdx.x;          // 131072
    int lane = g & 63;
    int nt = (g >> 6) & 15;
    int kb = (g >> 10) & 15;
    int kt = g >> 14;
    int n = nt * 16 + (lane & 15);
    int k0 = kb * 32 + ((lane >> 4) << 3);
    short8 hh = {0,0,0,0,0,0,0,0}, ll = {0,0,0,0,0,0,0,0};
    if (n < NN) {
        const float* wp = W + ((size_t)kt * NN + n) * DD + k0;
        floatx4 a = *(const floatx4*)wp;
        floatx4 b = *(const floatx4*)(wp + 4);
        float xv[8] = {a[0], a[1], a[2], a[3], b[0], b[1], b[2], b[3]};
        #pragma unroll
        for (int j = 0; j < 8; ++j) {
            unsigned h = bf16_rne(xv[j]);
            hh[j] = (short)h;
            ll[j] = (short)bf16_rne(xv[j] - __uint_as_float(h << 16));
        }
    }
    size_t base = ((((size_t)kt * 16 + kb) * 16 + nt) * 2) * 64;   // short8 units
    ((short8*)Bp)[base + lane] = hh;
    ((short8*)Bp)[base + 64 + lane] = ll;
}

// ---------------- fused forest kernel ----------------
__launch_bounds__(512, 2)
__global__ void k_forest(const short* __restrict__ xh, const short* __restrict__ xl,
                         const short* __restrict__ Bp, const float* __restrict__ bias,
                         const short* __restrict__ spf, float* __restrict__ tps) {
    __shared__ __align__(16) char smem[65536];
    const int tid  = threadIdx.x;
    const int lane = tid & 63;
    const int wv   = tid >> 6;
    const int wr   = wv >> 2;       // 0..1  (64-row half)
    const int wc   = wv & 3;        // 0..3  (64-col quarter)
    const int kt   = blockIdx.x;
    const int mb   = blockIdx.y;
    const int oct  = lane >> 4;
    const int lr   = lane & 15;

    const short* xhb = xh + (size_t)(mb * 128 + wr * 64 + lr) * DD + (oct << 3);
    const short* xlb = xl + (size_t)(mb * 128 + wr * 64 + lr) * DD + (oct << 3);
    const char* bsrc = (const char*)Bp + (size_t)kt * 16 * 32768;

    float breg[4];
    #pragma unroll
    for (int ntl = 0; ntl < 4; ++ntl) {
        int n = (wc * 4 + ntl) * 16 + lr;
        breg[ntl] = (n < NN) ? bias[kt * NN + n] : 0.f;
    }

    floatx4 acc[4][4];
    #pragma unroll
    for (int mt = 0; mt < 4; ++mt)
        #pragma unroll
        for (int ntl = 0; ntl < 4; ++ntl)
            acc[mt][ntl] = (floatx4){0.f, 0.f, 0.f, 0.f};

    short8 ahc[4], alc[4], ahn[4], aln[4];

    // prologue: stage kb=0, load A(0)
    #pragma unroll
    for (int i = 0; i < 4; ++i)
        gll16(bsrc + i * 8192 + tid * 16, (char*)smem + i * 8192 + tid * 16);
    #pragma unroll
    for (int mt = 0; mt < 4; ++mt) {
        ahc[mt] = *(const short8*)(xhb + (size_t)mt * 16 * DD);
        alc[mt] = *(const short8*)(xlb + (size_t)mt * 16 * DD);
    }
    __syncthreads();

    #pragma unroll 2
    for (int kb = 0; kb < 16; ++kb) {
        char* cur = (char*)smem + ((kb & 1) ? 32768 : 0);
        char* nxt = (char*)smem + ((kb & 1) ? 0 : 32768);
        if (kb < 15) {
            const char* s = bsrc + (size_t)(kb + 1) * 32768;
            #pragma unroll
            for (int i = 0; i < 4; ++i)
                gll16(s + i * 8192 + tid * 16, nxt + i * 8192 + tid * 16);
            #pragma unroll
            for (int mt = 0; mt < 4; ++mt) {
                ahn[mt] = *(const short8*)(xhb + (size_t)mt * 16 * DD + (kb + 1) * 32);
                aln[mt] = *(const short8*)(xlb + (size_t)mt * 16 * DD + (kb + 1) * 32);
            }
        }
        const short8* bf = (const short8*)cur;
        #pragma unroll
        for (int ntl = 0; ntl < 4; ++ntl) {
            const int nt = wc * 4 + ntl;
            short8 bh = bf[(size_t)(nt * 2 + 0) * 64 + lane];
            short8 bl = bf[(size_t)(nt * 2 + 1) * 64 + lane];
            #pragma unroll
            for (int mt = 0; mt < 4; ++mt) {
                acc[mt][ntl] = __builtin_amdgcn_mfma_f32_16x16x32_bf16(ahc[mt], bh, acc[mt][ntl], 0, 0, 0);
                acc[mt][ntl] = __builtin_amdgcn_mfma_f32_16x16x32_bf16(ahc[mt], bl, acc[mt][ntl], 0, 0, 0);
                acc[mt][ntl] = __builtin_amdgcn_mfma_f32_16x16x32_bf16(alc[mt], bh, acc[mt][ntl], 0, 0, 0);
            }
        }
        __syncthreads();
        #pragma unroll
        for (int mt = 0; mt < 4; ++mt) {
            ahc[mt] = ahn[mt]; alc[mt] = aln[mt];
        }
    }

    // ---------------- epilogue ----------------
    float* dls = (float*)smem;                                   // [32][260] fp32
    const short8* spl = (const short8*)((char*)smem + 33280);    // 16 KB frag copy
    floatx4* ps = (floatx4*)((char*)smem + 49664);               // 8 KB partials

    {   // stage sp frags
        const floatx4* src = (const floatx4*)(spf + (size_t)kt * 8192);
        floatx4* dst = (floatx4*)((char*)smem + 33280);
        dst[tid] = src[tid];
        dst[512 + tid] = src[512 + tid];
    }

    const int mtile = wv & 1;
    const int wg = wv >> 1;          // 0..3
    const int mloc = mtile * 16 + lr;

    #pragma unroll 1
    for (int p = 0; p < 4; ++p) {
        __syncthreads();
        if (wr == (p >> 1)) {
            const int mts = (p & 1) * 2;
            #pragma unroll
            for (int mtl = 0; mtl < 2; ++mtl)
                #pragma unroll
                for (int ntl = 0; ntl < 4; ++ntl)
                    #pragma unroll
                    for (int i = 0; i < 4; ++i) {
                        float lg = acc[mts + mtl][ntl][i] + breg[ntl];
                        float dv = 1.f / (1.f + __expf(-lg));
                        int mrow = mtl * 16 + oct * 4 + i;       // 0..31
                        int n = (wc * 4 + ntl) * 16 + lr;
                        dls[mrow * 260 + n] = dv;
                    }
        }
        __syncthreads();

        const float* dm = dls + mloc * 260;
        floatx4 pacc = (floatx4){0.f, 0.f, 0.f, 0.f};
        #pragma unroll
        for (int kss = 0; kss < 2; ++kss) {
            const int ks = wg * 2 + kss;
            const int leaf0 = ks * 32 + oct * 8;
            float d0 = dm[0];
            float d1 = dm[1 + (leaf0 >> 7)];
            float d2 = dm[3 + (leaf0 >> 6)];
            float d3 = dm[7 + (leaf0 >> 5)];
            float d4 = dm[15 + (leaf0 >> 4)];
            float d5 = dm[31 + (leaf0 >> 3)];
            float n6a = dm[63 + (leaf0 >> 2)];
            float n6b = dm[64 + (leaf0 >> 2)];
            float v70 = dm[127 + (leaf0 >> 1)];
            float v71 = dm[128 + (leaf0 >> 1)];
            float v72 = dm[129 + (leaf0 >> 1)];
            float v73 = dm[130 + (leaf0 >> 1)];
            float P = (((leaf0 >> 7) & 1) ? (1.f - d0) : d0)
                    * (((leaf0 >> 6) & 1) ? (1.f - d1) : d1)
                    * (((leaf0 >> 5) & 1) ? (1.f - d2) : d2)
                    * (((leaf0 >> 4) & 1) ? (1.f - d3) : d3)
                    * (((leaf0 >> 3) & 1) ? (1.f - d4) : d4);
            float pA = P * d5, pB = P * (1.f - d5);
            float q0 = pA * n6a, q1 = pA * (1.f - n6a);
            float q2 = pB * n6b, q3 = pB * (1.f - n6b);
            float mu[8];
            mu[0] = q0 * v70; mu[1] = q0 * (1.f - v70);
            mu[2] = q1 * v71; mu[3] = q1 * (1.f - v71);
            mu[4] = q2 * v72; mu[5] = q2 * (1.f - v72);
            mu[6] = q3 * v73; mu[7] = q3 * (1.f - v73);
            short8 mh, ml;
            #pragma unroll
            for (int j = 0; j < 8; ++j) {
                unsigned h = bf16_rne(mu[j]);
                mh[j] = (short)h;
                ml[j] = (short)bf16_rne(mu[j] - __uint_as_float(h << 16));
            }
            short8 sh = spl[(ks * 2 + 0) * 64 + lane];
            short8 sl = spl[(ks * 2 + 1) * 64 + lane];
            pacc = __builtin_amdgcn_mfma_f32_16x16x32_bf16(mh, sh, pacc, 0, 0, 0);
            pacc = __builtin_amdgcn_mfma_f32_16x16x32_bf16(mh, sl, pacc, 0, 0, 0);
            pacc = __builtin_amdgcn_mfma_f32_16x16x32_bf16(ml, sh, pacc, 0, 0, 0);
        }
        ps[(mtile * 4 + wg) * 64 + lane] = pacc;
        __syncthreads();
        if (wv < 2) {
            const int mt2 = wv;
            floatx4 r = ps[(mt2 * 4 + 0) * 64 + lane] + ps[(mt2 * 4 + 1) * 64 + lane]
                      + ps[(mt2 * 4 + 2) * 64 + lane] + ps[(mt2 * 4 + 3) * 64 + lane];
            #pragma unroll
            for (int i = 0; i < 4; ++i) {
                int mg = mb * 128 + p * 32 + mt2 * 16 + oct * 4 + i;
                int bb_ = mg >> 11, t = mg & 2047;
                tps[(size_t)bb_ * TPS_STRIDE + (size_t)t * 128 + lr * 8 + kt] = r[i];
            }
        }
    }
}

// ---------------- sequential scan ----------------
__device__ __forceinline__ float dpp_sum16(float v) {
    int i;
    i = __builtin_amdgcn_update_dpp(0, __float_as_int(v), 0xB1, 0xF, 0xF, true);
    v += __int_as_float(i);
    i = __builtin_amdgcn_update_dpp(0, __float_as_int(v), 0x4E, 0xF, 0xF, true);
    v += __int_as_float(i);
    i = __builtin_amdgcn_update_dpp(0, __float_as_int(v), 0x141, 0xF, 0xF, true);
    v += __int_as_float(i);
    i = __builtin_amdgcn_update_dpp(0, __float_as_int(v), 0x140, 0xF, 0xF, true);
    v += __int_as_float(i);
    return v;
}

__device__ __forceinline__ float rdl(float v, int k) {
    return __int_as_float(__builtin_amdgcn_readlane(__float_as_int(v), k));
}

#define SCAN_STEP(CA, CB, t) do { \
    float nw = ((CA[0]*w0 + CA[1]*w1) + (CA[2]*w2 + CA[3]*w3)) \
             + ((CB[0]*w4 + CB[1]*w5) + (CB[2]*w6 + CB[3]*w7)); \
    ob[(size_t)(t) * 16] = nw; \
    float wx = __expf(__expf(nw)); \
    CA = *(const floatx4*)(base + (size_t)((t) + 8) * 128); \
    CB = *(const floatx4*)(base + (size_t)((t) + 8) * 128 + 4); \
    float ssum = dpp_sum16(wx); \
    float wn = wx * __builtin_amdgcn_rcpf(ssum); \
    w0 = rdl(wn, 0); w1 = rdl(wn, 1); w2 = rdl(wn, 2); w3 = rdl(wn, 3); \
    w4 = rdl(wn, 4); w5 = rdl(wn, 5); w6 = rdl(wn, 6); w7 = rdl(wn, 7); \
} while (0)

__global__ void k_scan(const float* __restrict__ tps, float* __restrict__ out) {
    const int b = blockIdx.x;
    const int l = threadIdx.x;
    if (l >= 16) return;
    const float* base = tps + (size_t)b * TPS_STRIDE + l * 8;
    float* ob = out + (size_t)b * TT * 16 + l;
    float w0 = 1.f/16.f, w1 = 1.f/16.f, w2 = 1.f/16.f, w3 = 1.f/16.f;
    float w4 = 1.f/16.f, w5 = 1.f/16.f, w6 = 1.f/16.f, w7 = 1.f/16.f;
    floatx4 a0, a1, a2, a3, a4, a5, a6, a7;
    floatx4 b0, b1, b2, b3, b4, b5, b6, b7;
    a0 = *(const floatx4*)(base + 0*128); b0 = *(const floatx4*)(base + 0*128 + 4);
    a1 = *(const floatx4*)(base + 1*128); b1 = *(const floatx4*)(base + 1*128 + 4);
    a2 = *(const floatx4*)(base + 2*128); b2 = *(const floatx4*)(base + 2*128 + 4);
    a3 = *(const floatx4*)(base + 3*128); b3 = *(const floatx4*)(base + 3*128 + 4);
    a4 = *(const floatx4*)(base + 4*128); b4 = *(const floatx4*)(base + 4*128 + 4);
    a5 = *(const floatx4*)(base + 5*128); b5 = *(const floatx4*)(base + 5*128 + 4);
    a6 = *(const floatx4*)(base + 6*128); b6 = *(const floatx4*)(base + 6*128 + 4);
    a7 = *(const floatx4*)(base + 7*128); b7 = *(const floatx4*)(base + 7*128 + 4);
    for (int t0 = 0; t0 < TT; t0 += 8) {
        SCAN_STEP(a0, b0, t0 + 0);
        SCAN_STEP(a1, b1, t0 + 1);
        SCAN_STEP(a2, b2, t0 + 2);
        SCAN_STEP(a3, b3, t0 + 3);
        SCAN_STEP(a4, b4, t0 + 4);
        SCAN_STEP(a5, b5, t0 + 5);
        SCAN_STEP(a6, b6, t0 + 6);
        SCAN_STEP(a7, b7, t0 + 7);
    }
}

extern "C" void kernel_launch(void* const* d_in, const int* in_sizes, int n_in,
                              void* d_out, int out_size, void* d_ws, size_t ws_size,
                              hipStream_t stream) {
    const float* x  = (const float*)d_in[0];
    const float* W  = (const float*)d_in[1];
    const float* b  = (const float*)d_in[2];
    const float* pi = (const float*)d_in[3];
    float* ws = (float*)d_ws;
    float* tps = ws;                                   // 8,421,376 floats (32.1 MB)
    short* xh  = (short*)(ws + 8421376);               // 33,554,432 shorts
    short* xl  = xh + 33554432;
    short* Bp  = xl + 33554432;                        // 2,097,152 shorts
    short* spf = Bp + 2097152;                         // 65,536 shorts
    float* out = (float*)d_out;

    k_prep_x<<<dim3(16384), dim3(256), 0, stream>>>(x, xh, xl);
    k_prep_sp<<<dim3(8), dim3(256), 0, stream>>>(pi, spf);
    k_prep_b<<<dim3(512), dim3(256), 0, stream>>>(W, Bp);
    k_forest<<<dim3(8, 512), dim3(512), 0, stream>>>(xh, xl, Bp, b, spf, tps);
    k_scan<<<dim3(BB), dim3(64), 0, stream>>>(tps, out);
}